// Round 1
// baseline (565.801 us; speedup 1.0000x reference)
//
#include <hip/hip_runtime.h>
#include <stdint.h>

// B=8, T=4096, C=1024, NH=64, HD=16. M = B*T = 32768.

typedef __attribute__((ext_vector_type(8))) __bf16 bf16x8;
typedef __attribute__((ext_vector_type(4))) float f32x4;
typedef __attribute__((ext_vector_type(4))) unsigned int u32x4;
typedef __attribute__((ext_vector_type(4))) unsigned short u16x4;

#define AS1 __attribute__((address_space(1)))
#define AS3 __attribute__((address_space(3)))

__device__ __forceinline__ unsigned short f2bf(float f) {
  unsigned int u = __builtin_bit_cast(unsigned int, f);
  u += 0x7FFFu + ((u >> 16) & 1u);
  return (unsigned short)(u >> 16);
}

__device__ __forceinline__ void gl_lds16(const unsigned short* g, unsigned short* l) {
  __builtin_amdgcn_global_load_lds((const AS1 unsigned int*)g, (AS3 unsigned int*)l, 16, 0, 0);
}

// ---------------- fp32 -> bf16 convert ----------------
__global__ __launch_bounds__(256)
void cvt_f32_bf16(const float* __restrict__ src, unsigned short* __restrict__ dst, int n4) {
  int i = blockIdx.x * blockDim.x + threadIdx.x;
  const int stride = gridDim.x * blockDim.x;
  for (; i < n4; i += stride) {
    f32x4 v = *(const f32x4*)(src + (size_t)i * 4);
    u16x4 o;
    o.x = f2bf(v.x); o.y = f2bf(v.y); o.z = f2bf(v.z); o.w = f2bf(v.w);
    *(u16x4*)(dst + (size_t)i * 4) = o;
  }
}

// ---------------- 128x128-tile bf16 GEMM, out[m][n] = sum_k A[m][k]*Bw[n][k] + bias[n] ----
// MODE 0: q  -> softmax over 16-col head groups, bf16 natural [32768][1024]
// MODE 1: k  -> softmax, bf16 transposed per head [b][h][d][t]
// MODE 2: v  -> bf16 transposed per head [b][h][d][t]
// MODE 3: proj -> fp32 natural [32768][1024]
template<int MODE>
__global__ __launch_bounds__(256, 2)
void gemm_bt(const unsigned short* __restrict__ A,
             const unsigned short* __restrict__ Bw,
             const float* __restrict__ bias,
             void* __restrict__ outp)
{
  __shared__ __align__(16) unsigned short As[128 * 32];
  __shared__ __align__(16) unsigned short Bs[128 * 32];

  const int tid  = threadIdx.x;
  const int lane = tid & 63;
  const int wid  = tid >> 6;

  // XCD-bijective swizzle: 2048 blocks, 8 XCDs -> each XCD gets 32 contiguous brow panels.
  const int flat = blockIdx.x;
  const int vid  = (flat & 7) * 256 + (flat >> 3);
  const int brow = (vid >> 3) * 128;
  const int bcol = (vid & 7) * 128;

  // staging mapping: instr o (0/1): row = o*64 + wid*16 + lane/4, col8 = (lane%4)*8
  const int srow = wid * 16 + (lane >> 2);
  const int scol = (lane & 3) * 8;
  const unsigned short* a_src = A  + (size_t)(brow + srow) * 1024 + scol;
  const unsigned short* b_src = Bw + (size_t)(bcol + srow) * 1024 + scol;
  unsigned short* a_dst0 = &As[wid * 512];
  unsigned short* a_dst1 = &As[2048 + wid * 512];
  unsigned short* b_dst0 = &Bs[wid * 512];
  unsigned short* b_dst1 = &Bs[2048 + wid * 512];

  const int wm = (wid >> 1) * 64;   // wave output tile: 64x64
  const int wn = (wid & 1) * 64;
  const int fr = lane & 15;
  const int fg = lane >> 4;

  const f32x4 fz = {0.f, 0.f, 0.f, 0.f};
  f32x4 acc[4][4];
  #pragma unroll
  for (int mt = 0; mt < 4; ++mt)
    #pragma unroll
    for (int nt = 0; nt < 4; ++nt) acc[mt][nt] = fz;

  for (int k0 = 0; k0 < 1024; k0 += 32) {
    __syncthreads();   // previous iteration's ds_reads done before overwrite
    gl_lds16(a_src + k0,         a_dst0);
    gl_lds16(a_src + 65536 + k0, a_dst1);
    gl_lds16(b_src + k0,         b_dst0);
    gl_lds16(b_src + 65536 + k0, b_dst1);
    __syncthreads();   // compiler drains vmcnt(0) before s_barrier

    bf16x8 af[4], bf[4];
    #pragma unroll
    for (int mt = 0; mt < 4; ++mt)
      af[mt] = __builtin_bit_cast(bf16x8, *(const u32x4*)&As[(wm + mt * 16 + fr) * 32 + fg * 8]);
    #pragma unroll
    for (int nt = 0; nt < 4; ++nt)
      bf[nt] = __builtin_bit_cast(bf16x8, *(const u32x4*)&Bs[(wn + nt * 16 + fr) * 32 + fg * 8]);
    #pragma unroll
    for (int mt = 0; mt < 4; ++mt)
      #pragma unroll
      for (int nt = 0; nt < 4; ++nt)
        acc[mt][nt] = __builtin_amdgcn_mfma_f32_16x16x32_bf16(af[mt], bf[nt], acc[mt][nt], 0, 0, 0);
  }

  // Epilogue. C frag: col = lane&15, row = (lane>>4)*4 + r.
  #pragma unroll
  for (int nt = 0; nt < 4; ++nt) {
    const int n = bcol + wn + nt * 16 + fr;
    const float bv = bias[n];
    #pragma unroll
    for (int mt = 0; mt < 4; ++mt) {
      const int m0 = brow + wm + mt * 16 + fg * 4;
      float vals[4];
      #pragma unroll
      for (int r = 0; r < 4; ++r) vals[r] = acc[mt][nt][r] + bv;

      if (MODE == 0 || MODE == 1) {
        // softmax over the 16 columns (= one head's HD) of this fragment, per row r
        #pragma unroll
        for (int r = 0; r < 4; ++r) {
          float x = vals[r];
          float mx = x;
          #pragma unroll
          for (int s = 1; s < 16; s <<= 1) mx = fmaxf(mx, __shfl_xor(mx, s, 64));
          float e = __expf(x - mx);
          float sm = e;
          #pragma unroll
          for (int s = 1; s < 16; s <<= 1) sm += __shfl_xor(sm, s, 64);
          vals[r] = e / sm;
        }
      }

      if (MODE == 0) {
        unsigned short* o = (unsigned short*)outp;
        #pragma unroll
        for (int r = 0; r < 4; ++r)
          o[(size_t)(m0 + r) * 1024 + n] = f2bf(vals[r]);
      } else if (MODE == 1 || MODE == 2) {
        // transposed per head: dst[((b*64 + h)*16 + d)*4096 + t], 4 consecutive t -> one 8B store
        unsigned short* o = (unsigned short*)outp;
        const int bb = m0 >> 12;
        const int t0 = m0 & 4095;
        const int hh = n >> 4;
        const int dd = n & 15;
        u16x4 pk;
        pk.x = f2bf(vals[0]); pk.y = f2bf(vals[1]);
        pk.z = f2bf(vals[2]); pk.w = f2bf(vals[3]);
        *(u16x4*)&o[(((size_t)bb * 64 + hh) * 16 + dd) * 4096 + t0] = pk;
      } else {
        float* o = (float*)outp;
        #pragma unroll
        for (int r = 0; r < 4; ++r)
          o[(size_t)(m0 + r) * 1024 + n] = vals[r];
      }
    }
  }
}

// ---------------- per-head linear-attention middle ----------------
// Phase 1: ctx[d][e] = sum_t k[t][d] v[t][e]; kc[d] = sum_t k[t][d]   (MFMA, A=kT rows, B=vT rows)
// Phase 2: y[t][e] = (q[t,:] @ ctx) / (q[t,:] . kc)   via two zero-padded 16x16x32 MFMAs
__global__ __launch_bounds__(256)
void attn_kernel(const unsigned short* __restrict__ qb,
                 const unsigned short* __restrict__ kT,
                 const unsigned short* __restrict__ vT,
                 unsigned short* __restrict__ yb)
{
  const int head = blockIdx.x;           // b*64 + h
  const int tid  = threadIdx.x;
  const int lane = tid & 63;
  const int wid  = tid >> 6;
  const int fr   = lane & 15;
  const int fg   = lane >> 4;

  const unsigned short* kTh = kT + (size_t)head * 16 * 4096;
  const unsigned short* vTh = vT + (size_t)head * 16 * 4096;

  const u32x4 uz = {0u, 0u, 0u, 0u};
  const f32x4 fz = {0.f, 0.f, 0.f, 0.f};
  const u32x4 uo = {0x3F803F80u, 0x3F803F80u, 0x3F803F80u, 0x3F803F80u};
  const bf16x8 ones = __builtin_bit_cast(bf16x8, uo);

  f32x4 cctx = fz, ckc = fz;
  #pragma unroll 4
  for (int t0 = wid * 1024; t0 < (wid + 1) * 1024; t0 += 32) {
    bf16x8 ak = __builtin_bit_cast(bf16x8, *(const u32x4*)&kTh[(size_t)fr * 4096 + t0 + fg * 8]);
    bf16x8 bv = __builtin_bit_cast(bf16x8, *(const u32x4*)&vTh[(size_t)fr * 4096 + t0 + fg * 8]);
    cctx = __builtin_amdgcn_mfma_f32_16x16x32_bf16(ak, bv, cctx, 0, 0, 0);
    ckc  = __builtin_amdgcn_mfma_f32_16x16x32_bf16(ak, ones, ckc, 0, 0, 0);
  }

  __shared__ float red[4][16][16];
  __shared__ float kcr[4][16];
  __shared__ float ctxf[16][16];
  __shared__ float kcf[16];

  #pragma unroll
  for (int r = 0; r < 4; ++r) red[wid][fg * 4 + r][fr] = cctx[r];
  if (fr == 0) {
    #pragma unroll
    for (int r = 0; r < 4; ++r) kcr[wid][fg * 4 + r] = ckc[r];
  }
  __syncthreads();
  {
    const int d = tid >> 4, e = tid & 15;
    ctxf[d][e] = red[0][d][e] + red[1][d][e] + red[2][d][e] + red[3][d][e];
    if (tid < 16) kcf[tid] = kcr[0][tid] + kcr[1][tid] + kcr[2][tid] + kcr[3][tid];
  }
  __syncthreads();

  // B fragments (built once): k-index = fg*8+j; rows >=16 are zero padding
  bf16x8 bctx = __builtin_bit_cast(bf16x8, uz);
  bf16x8 bkc  = __builtin_bit_cast(bf16x8, uz);
  if (fg < 2) {
    #pragma unroll
    for (int j = 0; j < 8; ++j) {
      const int d = fg * 8 + j;
      bctx[j] = (__bf16)ctxf[d][fr];
      bkc[j]  = (__bf16)kcf[d];       // every column = kc -> denom lands in C layout
    }
  }

  const int b = head >> 6;
  const int h = head & 63;
  const size_t qbase = (size_t)b * 4096 * 1024 + (size_t)h * 16;

  for (int step = 0; step < 64; ++step) {
    const int t0 = step * 64 + wid * 16;
    bf16x8 af = __builtin_bit_cast(bf16x8, uz);
    if (fg < 2)
      af = __builtin_bit_cast(bf16x8, *(const u32x4*)&qb[qbase + (size_t)(t0 + fr) * 1024 + fg * 8]);
    f32x4 cy = __builtin_amdgcn_mfma_f32_16x16x32_bf16(af, bctx, fz, 0, 0, 0);
    f32x4 cd = __builtin_amdgcn_mfma_f32_16x16x32_bf16(af, bkc,  fz, 0, 0, 0);
    #pragma unroll
    for (int r = 0; r < 4; ++r) {
      const int t = t0 + fg * 4 + r;
      const float yv = cy[r] * __builtin_amdgcn_rcpf(cd[r]);
      yb[qbase + (size_t)t * 1024 + fr] = f2bf(yv);
    }
  }
}

// ---------------- launch ----------------
extern "C" void kernel_launch(void* const* d_in, const int* in_sizes, int n_in,
                              void* d_out, int out_size, void* d_ws, size_t ws_size,
                              hipStream_t stream)
{
  (void)in_sizes; (void)n_in; (void)out_size; (void)ws_size;
  const float* x  = (const float*)d_in[0];
  const float* Wq = (const float*)d_in[1];
  const float* bq = (const float*)d_in[2];
  const float* Wk = (const float*)d_in[3];
  const float* bk = (const float*)d_in[4];
  const float* Wv = (const float*)d_in[5];
  const float* bv = (const float*)d_in[6];
  const float* Wp = (const float*)d_in[7];
  const float* bp = (const float*)d_in[8];

  char* ws = (char*)d_ws;
  // requires ws_size >= 276,824,064 bytes
  unsigned short* xb  = (unsigned short*)(ws);              // 67108864 B; reused as yb after QKV
  unsigned short* wb  = (unsigned short*)(ws + 67108864);   // 4 x 2097152 B
  unsigned short* qb  = (unsigned short*)(ws + 75497472);   // 67108864 B
  unsigned short* kTb = (unsigned short*)(ws + 142606336);  // 67108864 B
  unsigned short* vTb = (unsigned short*)(ws + 209715200);  // 67108864 B

  cvt_f32_bf16<<<2048, 256, 0, stream>>>(x,  xb,            33554432 / 4);
  cvt_f32_bf16<<<1024, 256, 0, stream>>>(Wq, wb + 0,        1048576 / 4);
  cvt_f32_bf16<<<1024, 256, 0, stream>>>(Wk, wb + 1048576,  1048576 / 4);
  cvt_f32_bf16<<<1024, 256, 0, stream>>>(Wv, wb + 2097152,  1048576 / 4);
  cvt_f32_bf16<<<1024, 256, 0, stream>>>(Wp, wb + 3145728,  1048576 / 4);

  gemm_bt<0><<<2048, 256, 0, stream>>>(xb, wb + 0,       bq, (void*)qb);
  gemm_bt<1><<<2048, 256, 0, stream>>>(xb, wb + 1048576, bk, (void*)kTb);
  gemm_bt<2><<<2048, 256, 0, stream>>>(xb, wb + 2097152, bv, (void*)vTb);

  attn_kernel<<<512, 256, 0, stream>>>(qb, kTb, vTb, xb /* = yb */);

  gemm_bt<3><<<2048, 256, 0, stream>>>(xb /* yb */, wb + 3145728, bp, d_out);
}